// Round 2
// baseline (3339.248 us; speedup 1.0000x reference)
//
#include <hip/hip_runtime.h>
#include <math.h>

#define NB 16384

// ---- ws float offsets (total 30,495,296 floats = 116.3 MB) ----
static const size_t OFF_B    = 0;          // 25,690,112 (h2/h3 ; h4/h5) [B,1568]
static const size_t OFF_F    = 25690112;   //  3,670,016 (f1 / f3) [B,224]
static const size_t OFF_Z    = 29360128;   //    524,288
static const size_t OFF_ZQ   = 29884416;   //    524,288
static const size_t OFF_IDX  = 30408704;   //     16,384 (ints)
static const size_t OFF_CNT  = 30425088;   //        512
static const size_t OFF_SUM  = 30425600;   //     16,384
static const size_t OFF_LOSS = 30441984;   //         64
static const size_t OFF_WC2  = 30442048;   //      8,192
static const size_t OFF_WR1  = 30450240;   //     18,432
static const size_t OFF_WR2  = 30468672;   //     18,432
static const size_t OFF_WT1  = 30487104;   //      8,192

// Transpose weights into [k][co] layout for coalesced lane=co reads; zero loss accum.
__global__ __launch_bounds__(256) void k_prep(
    const float* __restrict__ w_c2, const float* __restrict__ w_r1,
    const float* __restrict__ w_r2, const float* __restrict__ w_t1,
    float* __restrict__ ws)
{
  int gid = blockIdx.x * 256 + threadIdx.x;
  if (gid == 0) ws[OFF_LOSS] = 0.f;
  for (int i = gid; i < 53248; i += 16384) {
    if (i < 8192) {                       // conv2: [co32][ci16][kk16] -> [(ci*16+kk)][co]
      int co = i & 31, rest = i >> 5, kk = rest & 15, ci = rest >> 4;
      ws[OFF_WC2 + i] = w_c2[co*256 + ci*16 + kk];
    } else if (i < 26624) {               // res1 w1: [co64][ci32][kk9] -> [(ci*9+kk)][co]
      int j = i - 8192, co = j & 63, rest = j >> 6, kk = rest % 9, ci = rest / 9;
      ws[OFF_WR1 + j] = w_r1[co*288 + ci*9 + kk];
    } else if (i < 45056) {               // res2 w1
      int j = i - 26624, co = j & 63, rest = j >> 6, kk = rest % 9, ci = rest / 9;
      ws[OFF_WR2 + j] = w_r2[co*288 + ci*9 + kk];
    } else {                              // convt1: [ci32][co16][kk16] -> [(ci*16+kk)][co]
      int j = i - 45056, co = j & 15, rest = j >> 4, kk = rest & 15, ci = rest >> 4;
      ws[OFF_WT1 + j] = w_t1[ci*256 + co*16 + kk];
    }
  }
}

// Fused encoder front: conv1(1->16,k4s2p1)+relu -> conv2(16->32,k4s2p1). One image/block.
__global__ __launch_bounds__(256) void k_enc(const float* __restrict__ x,
    const float* __restrict__ w1, const float* __restrict__ b1,
    const float* __restrict__ wT2, const float* __restrict__ b2,
    float* __restrict__ h2out)
{
  __shared__ float xin[30][32];       // [iy+1][ix+1], iy,ix in -1..28
  __shared__ float ph1[16][16][16];   // [ci][y+1][x+1], y,x in -1..14
  __shared__ float outl[1568];
  int b = blockIdx.x, t = threadIdx.x;
  float* xp = &xin[0][0];
  for (int i = t; i < 960; i += 256) xp[i] = 0.f;
  float* pp = &ph1[0][0][0];
  for (int i = t; i < 4096; i += 256) pp[i] = 0.f;
  __syncthreads();
  const float* xb = x + b*784;
  for (int i = t; i < 784; i += 256) {
    int y = i/28, xx = i%28;
    xin[y+1][xx+1] = xb[i];
  }
  __syncthreads();
  // conv1: 16co x 14x14
  for (int i = t; i < 3136; i += 256) {
    int co = i / 196, p = i % 196, oy = p/14, ox = p%14;
    float acc = b1[co];
    #pragma unroll
    for (int ky = 0; ky < 4; ++ky)
      #pragma unroll
      for (int kx = 0; kx < 4; ++kx)
        acc += xin[2*oy+ky][2*ox+kx] * w1[co*16 + ky*4 + kx];
    ph1[co][oy+1][ox+1] = fmaxf(acc, 0.f);
  }
  __syncthreads();
  // conv2: lane=co (0..31), ys = t>>5 (valid <7)
  int co = t & 31, ys = t >> 5;
  float acc[7];
  #pragma unroll
  for (int j = 0; j < 7; ++j) acc[j] = 0.f;
  if (ys < 7) {
    for (int ci = 0; ci < 16; ++ci) {
      float fr[4][16];
      #pragma unroll
      for (int r = 0; r < 4; ++r) {        // piy = 2y + ky
        const float4* rp = (const float4*)&ph1[ci][2*ys + r][0];
        float4 a = rp[0], bq = rp[1], c = rp[2], d = rp[3];
        fr[r][0]=a.x;  fr[r][1]=a.y;  fr[r][2]=a.z;  fr[r][3]=a.w;
        fr[r][4]=bq.x; fr[r][5]=bq.y; fr[r][6]=bq.z; fr[r][7]=bq.w;
        fr[r][8]=c.x;  fr[r][9]=c.y;  fr[r][10]=c.z; fr[r][11]=c.w;
        fr[r][12]=d.x; fr[r][13]=d.y; fr[r][14]=d.z; fr[r][15]=d.w;
      }
      #pragma unroll
      for (int ky = 0; ky < 4; ++ky) {
        #pragma unroll
        for (int kx = 0; kx < 4; ++kx) {
          float wv = wT2[(ci*16 + ky*4 + kx)*32 + co];
          #pragma unroll
          for (int xx = 0; xx < 7; ++xx)
            acc[xx] += fr[ky][2*xx + kx] * wv;
        }
      }
    }
    float bv = b2[co];
    #pragma unroll
    for (int xx = 0; xx < 7; ++xx) outl[co*49 + ys*7 + xx] = acc[xx] + bv;
  }
  __syncthreads();
  float* dst = h2out + b*1568;
  for (int i = t; i < 1568; i += 256) dst[i] = outl[i];
}

// Fused residual stack: relu -> conv3x3(32->64) -> relu -> conv1x1(64->32) -> +x -> relu.
// In-place on h [b][32][49]. One image per block, 448 threads.
__global__ __launch_bounds__(448) void k_res(float* __restrict__ h,
    const float* __restrict__ wT, const float* __restrict__ w2)
{
  __shared__ float pin[32][9][12];   // relu(h) padded
  __shared__ float rl[49][64];       // conv3x3 output [pixel][co]
  __shared__ float hraw[1568];
  __shared__ float outl[1568];
  int b = blockIdx.x, t = threadIdx.x;
  float* ps = &pin[0][0][0];
  for (int i = t; i < 3456; i += 448) ps[i] = 0.f;
  __syncthreads();
  float* hb = h + b*1568;
  for (int i = t; i < 1568; i += 448) {
    float v = hb[i];
    hraw[i] = v;
    int ci = i/49, p = i%49, y = p/7, xx = p%7;
    pin[ci][y+1][xx+1] = fmaxf(v, 0.f);
  }
  __syncthreads();
  // conv3x3: lane = co (0..63), wy = y (0..6)
  {
    int lane = t & 63, wy = t >> 6;
    float acc[7];
    #pragma unroll
    for (int j = 0; j < 7; ++j) acc[j] = 0.f;
    for (int ci = 0; ci < 32; ++ci) {
      float rb[3][9];
      #pragma unroll
      for (int r = 0; r < 3; ++r) {
        const float4* rp = (const float4*)&pin[ci][wy + r][0];
        float4 a = rp[0], bq = rp[1], c = rp[2];
        rb[r][0]=a.x;  rb[r][1]=a.y;  rb[r][2]=a.z;  rb[r][3]=a.w;
        rb[r][4]=bq.x; rb[r][5]=bq.y; rb[r][6]=bq.z; rb[r][7]=bq.w;
        rb[r][8]=c.x;
      }
      #pragma unroll
      for (int ky = 0; ky < 3; ++ky) {
        #pragma unroll
        for (int kx = 0; kx < 3; ++kx) {
          float wv = wT[(ci*9 + ky*3 + kx)*64 + lane];
          #pragma unroll
          for (int xx = 0; xx < 7; ++xx)
            acc[xx] += rb[ky][xx + kx] * wv;
        }
      }
    }
    #pragma unroll
    for (int xx = 0; xx < 7; ++xx)
      rl[wy*7 + xx][lane] = fmaxf(acc[xx], 0.f);
  }
  __syncthreads();
  // conv1x1 + residual + relu: co = t&31, pq = t>>5 (0..13), p = pq, pq+14, pq+28, pq+42
  {
    int co = t & 31, pq = t >> 5;
    for (int p = pq; p < 49; p += 14) {
      float a = 0.f;
      #pragma unroll
      for (int cq = 0; cq < 16; ++cq) {
        float4 wv = *(const float4*)&w2[co*64 + cq*4];
        float4 rv = *(const float4*)&rl[p][cq*4];
        a += wv.x*rv.x + wv.y*rv.y + wv.z*rv.z + wv.w*rv.w;
      }
      outl[co*49 + p] = fmaxf(hraw[co*49 + p] + a, 0.f);
    }
  }
  __syncthreads();
  for (int i = t; i < 1568; i += 448) hb[i] = outl[i];
}

// Generic fp32 GEMM: C[M,N] = A[M,K] * W[N,K]^T + bias (optionally relu).
// Requires M%64==0, N%32==0, K%16==0 (all call sites satisfy this).
__global__ __launch_bounds__(256) void k_gemm(const float* __restrict__ A,
    const float* __restrict__ W, const float* __restrict__ bias,
    float* __restrict__ C, int M, int N, int K, int relu)
{
  __shared__ float As[16][64];
  __shared__ float Bs[16][32];
  int bm = blockIdx.x * 64, bn = blockIdx.y * 32;
  int t = threadIdx.x;
  int tn = t & 15, tm = t >> 4;
  int lm = t >> 2, lk = (t & 3) * 4;
  float acc[4][2];
  #pragma unroll
  for (int i = 0; i < 4; ++i) { acc[i][0] = 0.f; acc[i][1] = 0.f; }
  for (int k0 = 0; k0 < K; k0 += 16) {
    float4 av = *(const float4*)&A[(bm + lm)*K + k0 + lk];
    float4 bv = {0,0,0,0};
    if (t < 128) bv = *(const float4*)&W[(bn + (t >> 2))*K + k0 + lk];
    __syncthreads();
    As[lk+0][lm]=av.x; As[lk+1][lm]=av.y; As[lk+2][lm]=av.z; As[lk+3][lm]=av.w;
    if (t < 128) { int ln = t >> 2;
      Bs[lk+0][ln]=bv.x; Bs[lk+1][ln]=bv.y; Bs[lk+2][ln]=bv.z; Bs[lk+3][ln]=bv.w; }
    __syncthreads();
    #pragma unroll
    for (int k = 0; k < 16; ++k) {
      const float4 a = *(const float4*)&As[k][tm*4];
      const float2 bb = *(const float2*)&Bs[k][tn*2];
      acc[0][0] += a.x*bb.x; acc[0][1] += a.x*bb.y;
      acc[1][0] += a.y*bb.x; acc[1][1] += a.y*bb.y;
      acc[2][0] += a.z*bb.x; acc[2][1] += a.z*bb.y;
      acc[3][0] += a.w*bb.x; acc[3][1] += a.w*bb.y;
    }
  }
  #pragma unroll
  for (int i = 0; i < 4; ++i) {
    int m = bm + tm*4 + i;
    #pragma unroll
    for (int j = 0; j < 2; ++j) {
      int n = bn + tn*2 + j;
      float v = acc[i][j] + bias[n];
      if (relu) v = fmaxf(v, 0.f);
      C[m*N + n] = v;
    }
  }
}

// VQ: per-row argmin over 512 codes (first-index ties), zq gather, commit-loss partial sum.
__global__ __launch_bounds__(256) void k_vq_assign(const float* __restrict__ z,
    const float* __restrict__ emb, float* __restrict__ zq, int* __restrict__ idx,
    float* __restrict__ loss)
{
  __shared__ float esq[512];
  int t = threadIdx.x;
  int n = blockIdx.x * 256 + t;
  for (int e = t; e < 512; e += 256) {
    const float4* ep = (const float4*)&emb[e*32];
    float s = 0.f;
    #pragma unroll
    for (int q = 0; q < 8; ++q) { float4 v = ep[q]; s += v.x*v.x + v.y*v.y + v.z*v.z + v.w*v.w; }
    esq[e] = s;
  }
  __syncthreads();
  float zv[32];
  const float4* zp = (const float4*)&z[n*32];
  float zz = 0.f;
  #pragma unroll
  for (int q = 0; q < 8; ++q) {
    float4 v = zp[q];
    zv[4*q]=v.x; zv[4*q+1]=v.y; zv[4*q+2]=v.z; zv[4*q+3]=v.w;
    zz += v.x*v.x + v.y*v.y + v.z*v.z + v.w*v.w;
  }
  float best = 3.4e38f; int bi = 0;
  for (int e = 0; e < 512; ++e) {
    const float4* ep = (const float4*)&emb[e*32];
    float dot = 0.f;
    #pragma unroll
    for (int q = 0; q < 8; ++q) {
      float4 v = ep[q];
      dot += zv[4*q]*v.x + zv[4*q+1]*v.y + zv[4*q+2]*v.z + zv[4*q+3]*v.w;
    }
    float d = zz + esq[e] - 2.f*dot;
    if (d < best) { best = d; bi = e; }
  }
  idx[n] = bi;
  const float4* bp = (const float4*)&emb[bi*32];
  float4* zo = (float4*)&zq[n*32];
  float ls = 0.f;
  #pragma unroll
  for (int q = 0; q < 8; ++q) {
    float4 v = bp[q]; zo[q] = v;
    float d0 = v.x - zv[4*q], d1 = v.y - zv[4*q+1];
    float d2 = v.z - zv[4*q+2], d3 = v.w - zv[4*q+3];
    ls += d0*d0 + d1*d1 + d2*d2 + d3*d3;
  }
  #pragma unroll
  for (int m = 32; m >= 1; m >>= 1) ls += __shfl_xor(ls, m);
  if ((t & 63) == 0) atomicAdd(loss, ls);
}

// Per-code segment reduction: counts[e], sums[e][32]. One wave per code.
__global__ __launch_bounds__(64) void k_vq_reduce(const int* __restrict__ idx,
    const float* __restrict__ z, float* __restrict__ counts, float* __restrict__ sums)
{
  int e = blockIdx.x, t = threadIdx.x;
  float cnt = 0.f, sv[32];
  #pragma unroll
  for (int k = 0; k < 32; ++k) sv[k] = 0.f;
  for (int n = t; n < 16384; n += 64) {
    if (idx[n] == e) {
      cnt += 1.f;
      const float4* zp = (const float4*)&z[n*32];
      #pragma unroll
      for (int q = 0; q < 8; ++q) {
        float4 v = zp[q];
        sv[4*q] += v.x; sv[4*q+1] += v.y; sv[4*q+2] += v.z; sv[4*q+3] += v.w;
      }
    }
  }
  #pragma unroll
  for (int m = 32; m >= 1; m >>= 1) {
    cnt += __shfl_xor(cnt, m);
    #pragma unroll
    for (int k = 0; k < 32; ++k) sv[k] += __shfl_xor(sv[k], m);
  }
  if (t == 0) {
    counts[e] = cnt;
    #pragma unroll
    for (int k = 0; k < 32; ++k) sums[e*32 + k] = sv[k];
  }
}

// EMA update, emb_new, perplexity, losses.
__global__ __launch_bounds__(512) void k_vq_final(const float* __restrict__ counts,
    const float* __restrict__ sums, const float* __restrict__ n_mat,
    const float* __restrict__ m_mat, const float* __restrict__ loss,
    float* __restrict__ out)
{
  __shared__ float red[8];
  int t = threadIdx.x;
  float c = counts[t];
  float nn = n_mat[t]*0.99f + c*0.01f;
  #pragma unroll
  for (int k = 0; k < 32; ++k) {
    float mn = m_mat[t*32+k]*0.99f + sums[t*32+k]*0.01f;
    out[12845059 + t*32 + k] = mn / nn;
  }
  float em = c * (1.f/16384.f);
  float ht = em * logf(em + 1e-10f);
  #pragma unroll
  for (int m = 32; m >= 1; m >>= 1) ht += __shfl_xor(ht, m);
  if ((t & 63) == 0) red[t >> 6] = ht;
  __syncthreads();
  if (t == 0) {
    float H = 0.f;
    #pragma unroll
    for (int i = 0; i < 8; ++i) H += red[i];
    float q = loss[0] * (1.f/524288.f);
    out[12845056] = q;           // quant_loss
    out[12845057] = q;           // commit_loss (BETA = 1.0)
    out[12845058] = expf(-H);    // perplexity
  }
}

// Fused decoder tail: convT1(32->16,k4s2p1)+relu -> convT2(16->1,k4s2p1). One image/block.
__global__ __launch_bounds__(512) void k_dec(const float* __restrict__ h5,
    const float* __restrict__ wT1, const float* __restrict__ bt1,
    const float* __restrict__ wt2, const float* __restrict__ bt2,
    float* __restrict__ out)
{
  __shared__ float pin[32][9][12];     // h5 padded (raw)
  __shared__ float pt1[16][16][16];    // t1 [ci][iy+1][ix+1], iy,ix in -1..14, zero borders
  int b = blockIdx.x, t = threadIdx.x;
  float* ps = &pin[0][0][0];
  for (int i = t; i < 3456; i += 512) ps[i] = 0.f;
  float* pq = &pt1[0][0][0];
  for (int i = t; i < 4096; i += 512) pq[i] = 0.f;
  __syncthreads();
  const float* src = h5 + b*1568;
  for (int i = t; i < 1568; i += 512) {
    int ci = i / 49, p = i % 49, y = p / 7, xx = p % 7;
    pin[ci][y+1][xx+1] = src[i];
  }
  __syncthreads();
  // convT1 via parity decomposition: co = t&15, pc = (t>>4)>>3, yy = (t>>4)&7 (valid <7)
  {
    int co = t & 15, rest = t >> 4;
    int pc = rest >> 3, yy = rest & 7;
    int py = pc >> 1, px = pc & 1;
    if (yy < 7) {
      float acc[7];
      float bv = bt1[co];
      #pragma unroll
      for (int j = 0; j < 7; ++j) acc[j] = bv;
      for (int ci = 0; ci < 32; ++ci) {
        #pragma unroll
        for (int r = 0; r < 2; ++r) {
          const float* rowp = &pin[ci][yy + py + r][px];
          float fr[8];
          #pragma unroll
          for (int u = 0; u < 8; ++u) fr[u] = rowp[u];
          int ky = 3 - py - 2*r;
          #pragma unroll
          for (int cc = 0; cc < 2; ++cc) {
            int kx = 3 - px - 2*cc;
            float wv = wT1[(ci*16 + ky*4 + kx)*16 + co];
            #pragma unroll
            for (int xx = 0; xx < 7; ++xx)
              acc[xx] += fr[xx + cc] * wv;
          }
        }
      }
      int oy = 2*yy + py;
      #pragma unroll
      for (int xx = 0; xx < 7; ++xx) {
        int ox = 2*xx + px;
        pt1[co][oy + 1][ox + 1] = fmaxf(acc[xx], 0.f);
      }
    }
  }
  __syncthreads();
  // convT2: 784 output pixels; padded pt1 makes boundary guards free
  for (int p = t; p < 784; p += 512) {
    int oy = p / 28, ox = p % 28;
    int qy = (oy + 1) & 1, qx = (ox + 1) & 1;
    int iy1 = (oy + 1 - qy) >> 1, iy2 = iy1 - 1;
    int ix1 = (ox + 1 - qx) >> 1, ix2 = ix1 - 1;
    float acc = bt2[0];
    #pragma unroll
    for (int ci = 0; ci < 16; ++ci) {
      const float* wc = wt2 + ci*16;
      acc += pt1[ci][iy1+1][ix1+1] * wc[qy*4 + qx]
           + pt1[ci][iy1+1][ix2+1] * wc[qy*4 + qx + 2]
           + pt1[ci][iy2+1][ix1+1] * wc[(qy+2)*4 + qx]
           + pt1[ci][iy2+1][ix2+1] * wc[(qy+2)*4 + qx + 2];
    }
    out[b*784 + p] = acc;
  }
}

extern "C" void kernel_launch(void* const* d_in, const int* in_sizes, int n_in,
                              void* d_out, int out_size, void* d_ws, size_t ws_size,
                              hipStream_t stream)
{
  const float* x    = (const float*)d_in[0];
  const float* c1w  = (const float*)d_in[1];
  const float* c1b  = (const float*)d_in[2];
  const float* c2w  = (const float*)d_in[3];
  const float* c2b  = (const float*)d_in[4];
  const float* r1w1 = (const float*)d_in[5];
  const float* r1w2 = (const float*)d_in[6];
  const float* fc1w = (const float*)d_in[7];
  const float* fc1b = (const float*)d_in[8];
  const float* fc2w = (const float*)d_in[9];
  const float* fc2b = (const float*)d_in[10];
  const float* emb  = (const float*)d_in[11];
  const float* nmat = (const float*)d_in[12];
  const float* mmat = (const float*)d_in[13];
  const float* fc3w = (const float*)d_in[14];
  const float* fc3b = (const float*)d_in[15];
  const float* fc4w = (const float*)d_in[16];
  const float* fc4b = (const float*)d_in[17];
  const float* r2w1 = (const float*)d_in[18];
  const float* r2w2 = (const float*)d_in[19];
  const float* t1w  = (const float*)d_in[20];
  const float* t1b  = (const float*)d_in[21];
  const float* t2w  = (const float*)d_in[22];
  const float* t2b  = (const float*)d_in[23];
  float* ws  = (float*)d_ws;
  float* out = (float*)d_out;

  float* bufB = ws + OFF_B;
  float* f1   = ws + OFF_F;
  float* z    = ws + OFF_Z;
  float* zq   = ws + OFF_ZQ;
  int*   idx  = (int*)(ws + OFF_IDX);
  float* cnts = ws + OFF_CNT;
  float* sums = ws + OFF_SUM;
  float* loss = ws + OFF_LOSS;
  float* wc2  = ws + OFF_WC2;
  float* wr1  = ws + OFF_WR1;
  float* wr2  = ws + OFF_WR2;
  float* wt1  = ws + OFF_WT1;

  k_prep<<<64, 256, 0, stream>>>(c2w, r1w1, r2w1, t1w, ws);
  k_enc<<<NB, 256, 0, stream>>>(x, c1w, c1b, wc2, c2b, bufB);
  k_res<<<NB, 448, 0, stream>>>(bufB, wr1, r1w2);
  k_gemm<<<dim3(256, 7),  256, 0, stream>>>(bufB, fc1w, fc1b, f1, 16384, 224, 1568, 1);
  k_gemm<<<dim3(256, 1),  256, 0, stream>>>(f1, fc2w, fc2b, z, 16384, 32, 224, 0);
  k_vq_assign<<<64, 256, 0, stream>>>(z, emb, zq, idx, loss);
  k_vq_reduce<<<512, 64, 0, stream>>>(idx, z, cnts, sums);
  k_vq_final<<<1, 512, 0, stream>>>(cnts, sums, nmat, mmat, loss, out);
  k_gemm<<<dim3(256, 7),  256, 0, stream>>>(zq, fc3w, fc3b, f1, 16384, 224, 32, 1);
  k_gemm<<<dim3(256, 49), 256, 0, stream>>>(f1, fc4w, fc4b, bufB, 16384, 1568, 224, 1);
  k_res<<<NB, 448, 0, stream>>>(bufB, wr2, r2w2);
  k_dec<<<NB, 512, 0, stream>>>(bufB, wt1, t1b, t2w, t2b, out);
}

// Round 3
// 1599.314 us; speedup vs baseline: 2.0879x; 2.0879x over previous
//
#include <hip/hip_runtime.h>
#include <math.h>

#define NB 16384
typedef unsigned short ushort_t;
typedef unsigned int uint_t;
typedef __attribute__((ext_vector_type(8))) short short8;
typedef __attribute__((ext_vector_type(4))) float fx4;

// ---- ws float offsets (total 17,730,112 floats = 70.9 MB) ----
static const size_t OFF_HB    = 0;          // ushort[16384*1568] bf16 (h2/h3/h4/h5)
static const size_t OFF_F1B   = 12845056;   // ushort[16384*224]
static const size_t OFF_F3B   = 14680064;   // ushort[16384*224]
static const size_t OFF_Z     = 16515072;   // float[524288]
static const size_t OFF_IDX   = 17039360;   // int[16384]
static const size_t OFF_ZQB   = 17055744;   // ushort[524288]
static const size_t OFF_CNT   = 17317888;   // float[512]
static const size_t OFF_SUM   = 17318400;   // float[16384]
static const size_t OFF_LOSS  = 17334784;   // float[64]
static const size_t OFF_WC2   = 17334848;   // float[8192]
static const size_t OFF_WT1   = 17343040;   // float[8192]
static const size_t OFF_WR1B  = 17351232;   // ushort[18432]  [9][64][32]
static const size_t OFF_WR2B  = 17360448;   // ushort[18432]
static const size_t OFF_W2B1  = 17369664;   // ushort[2048]   [32][64]
static const size_t OFF_W2B2  = 17370688;   // ushort[2048]
static const size_t OFF_FC1WB = 17371712;   // ushort[351232] [224][1568]
static const size_t OFF_FC2WB = 17547328;   // ushort[7168]   [32][224]
static const size_t OFF_FC3WB = 17550912;   // ushort[7168]   [224][32]
static const size_t OFF_FC4WB = 17554496;   // ushort[351232] [1568][224]

static __device__ __forceinline__ ushort_t f2bf(float f) {
  union { float f; uint_t u; } v; v.f = f;
  return (ushort_t)((v.u + 0x7fffu + ((v.u >> 16) & 1u)) >> 16);
}
static __device__ __forceinline__ float bf2f(ushort_t h) {
  union { uint_t u; float f; } v; v.u = ((uint_t)h) << 16;
  return v.f;
}

// Weight prep: transposes + fp32->bf16 conversions; zero loss accumulator.
__global__ __launch_bounds__(256) void k_prep(
    const float* __restrict__ c2w, const float* __restrict__ r1w1,
    const float* __restrict__ r1w2, const float* __restrict__ r2w1,
    const float* __restrict__ r2w2, const float* __restrict__ t1w,
    const float* __restrict__ fc1w, const float* __restrict__ fc2w,
    const float* __restrict__ fc3w, const float* __restrict__ fc4w,
    float* __restrict__ ws)
{
  int gid = blockIdx.x * 256 + threadIdx.x;
  if (gid == 0) ws[OFF_LOSS] = 0.f;
  if (gid >= 774144) return;
  float* wc2 = ws + OFF_WC2;
  float* wt1 = ws + OFF_WT1;
  ushort_t* wr1b  = (ushort_t*)(ws + OFF_WR1B);
  ushort_t* wr2b  = (ushort_t*)(ws + OFF_WR2B);
  ushort_t* w2b1  = (ushort_t*)(ws + OFF_W2B1);
  ushort_t* w2b2  = (ushort_t*)(ws + OFF_W2B2);
  ushort_t* fc1wb = (ushort_t*)(ws + OFF_FC1WB);
  ushort_t* fc2wb = (ushort_t*)(ws + OFF_FC2WB);
  ushort_t* fc3wb = (ushort_t*)(ws + OFF_FC3WB);
  ushort_t* fc4wb = (ushort_t*)(ws + OFF_FC4WB);
  int i = gid;
  if (i < 8192) {                       // conv2 wT fp32: [(ci*16+kk)][co]
    int co = i & 31, rest = i >> 5, kk = rest & 15, ci = rest >> 4;
    wc2[i] = c2w[co*256 + ci*16 + kk];
  } else if (i < 16384) {               // convt1 wT fp32
    int j = i - 8192, co = j & 15, rest = j >> 4, kk = rest & 15, ci = rest >> 4;
    wt1[j] = t1w[ci*256 + co*16 + kk];
  } else if (i < 34816) {               // res1 w1 -> [kk][co][ci] bf16
    int j = i - 16384, ci = j & 31, r = j >> 5, co = r & 63, kk = r >> 6;
    wr1b[j] = f2bf(r1w1[co*288 + ci*9 + kk]);
  } else if (i < 53248) {               // res2 w1
    int j = i - 34816, ci = j & 31, r = j >> 5, co = r & 63, kk = r >> 6;
    wr2b[j] = f2bf(r2w1[co*288 + ci*9 + kk]);
  } else if (i < 55296) {               // res1 w2 [32][64] bf16
    int j = i - 53248; w2b1[j] = f2bf(r1w2[j]);
  } else if (i < 57344) {               // res2 w2
    int j = i - 55296; w2b2[j] = f2bf(r2w2[j]);
  } else if (i < 408576) {              // fc1 [224][1568]
    int j = i - 57344; fc1wb[j] = f2bf(fc1w[j]);
  } else if (i < 415744) {              // fc2 [32][224]
    int j = i - 408576; fc2wb[j] = f2bf(fc2w[j]);
  } else if (i < 422912) {              // fc3 [224][32]
    int j = i - 415744; fc3wb[j] = f2bf(fc3w[j]);
  } else {                              // fc4 [1568][224]
    int j = i - 422912; fc4wb[j] = f2bf(fc4w[j]);
  }
}

// Fused encoder: conv1(1->16,k4s2p1)+relu -> conv2(16->32,k4s2p1), out bf16. One image/block.
__global__ __launch_bounds__(256) void k_enc(const float* __restrict__ x,
    const float* __restrict__ w1, const float* __restrict__ b1,
    const float* __restrict__ wT2, const float* __restrict__ b2,
    ushort_t* __restrict__ hb)
{
  __shared__ float xin[30][32];
  __shared__ float ph1[16][16][16];
  __shared__ float outl[1568];
  int b = blockIdx.x, t = threadIdx.x;
  float* xp = &xin[0][0];
  for (int i = t; i < 960; i += 256) xp[i] = 0.f;
  float* pp = &ph1[0][0][0];
  for (int i = t; i < 4096; i += 256) pp[i] = 0.f;
  __syncthreads();
  const float* xb = x + b*784;
  for (int i = t; i < 784; i += 256) {
    int y = i/28, xx = i%28;
    xin[y+1][xx+1] = xb[i];
  }
  __syncthreads();
  for (int i = t; i < 3136; i += 256) {
    int co = i / 196, p = i % 196, oy = p/14, ox = p%14;
    float acc = b1[co];
    #pragma unroll
    for (int ky = 0; ky < 4; ++ky)
      #pragma unroll
      for (int kx = 0; kx < 4; ++kx)
        acc += xin[2*oy+ky][2*ox+kx] * w1[co*16 + ky*4 + kx];
    ph1[co][oy+1][ox+1] = fmaxf(acc, 0.f);
  }
  __syncthreads();
  int co = t & 31, ys = t >> 5;
  float acc[7];
  #pragma unroll
  for (int j = 0; j < 7; ++j) acc[j] = 0.f;
  if (ys < 7) {
    for (int ci = 0; ci < 16; ++ci) {
      float fr[4][16];
      #pragma unroll
      for (int r = 0; r < 4; ++r) {
        const float4* rp = (const float4*)&ph1[ci][2*ys + r][0];
        float4 a = rp[0], bq = rp[1], c = rp[2], d = rp[3];
        fr[r][0]=a.x;  fr[r][1]=a.y;  fr[r][2]=a.z;  fr[r][3]=a.w;
        fr[r][4]=bq.x; fr[r][5]=bq.y; fr[r][6]=bq.z; fr[r][7]=bq.w;
        fr[r][8]=c.x;  fr[r][9]=c.y;  fr[r][10]=c.z; fr[r][11]=c.w;
        fr[r][12]=d.x; fr[r][13]=d.y; fr[r][14]=d.z; fr[r][15]=d.w;
      }
      #pragma unroll
      for (int ky = 0; ky < 4; ++ky) {
        #pragma unroll
        for (int kx = 0; kx < 4; ++kx) {
          float wv = wT2[(ci*16 + ky*4 + kx)*32 + co];
          #pragma unroll
          for (int xx = 0; xx < 7; ++xx)
            acc[xx] += fr[ky][2*xx + kx] * wv;
        }
      }
    }
    float bv = b2[co];
    #pragma unroll
    for (int xx = 0; xx < 7; ++xx) outl[co*49 + ys*7 + xx] = acc[xx] + bv;
  }
  __syncthreads();
  uint_t* dst = (uint_t*)(hb + (size_t)b*1568);
  for (int j = t; j < 784; j += 256)
    dst[j] = (uint_t)f2bf(outl[2*j]) | ((uint_t)f2bf(outl[2*j+1]) << 16);
}

// MFMA residual stack: relu -> conv3x3(32->64) -> relu -> conv1x1(64->32) -> +x -> relu.
// In/out bf16 [b][32][49], in-place. 256 threads = 4 waves per image.
__global__ __launch_bounds__(256) void k_res(ushort_t* __restrict__ hb,
    const ushort_t* __restrict__ wrb, const ushort_t* __restrict__ w2b)
{
  __shared__ ushort_t pinT[3456];   // [pp=108][ci=32], swizzled (64B rows)
  __shared__ ushort_t rl[4096];     // [pix=64][co=64], swizzled (128B rows)
  __shared__ ushort_t hrawb[1568];
  __shared__ ushort_t outl[1568];
  int b = blockIdx.x, t = threadIdx.x, l = t & 63, w = t >> 6, g = l >> 4;

  // B-frags for conv3x3: wave w owns co tile [w*16, w*16+16)
  short8 bfr[9];
  #pragma unroll
  for (int o = 0; o < 9; ++o)
    bfr[o] = *(const short8*)(wrb + (size_t)(o*64 + w*16 + (l & 15))*32 + g*8);

  // zero pinT
  uint_t* pz = (uint_t*)pinT;
  for (int i = t; i < 1728; i += 256) pz[i] = 0;
  __syncthreads();

  // stage: read bf16 image, keep raw, write relu'd into padded swizzled pinT
  const uint_t* src = (const uint_t*)(hb + (size_t)b*1568);
  char* pinc = (char*)pinT;
  for (int j = t; j < 784; j += 256) {
    uint_t u = src[j];
    ((uint_t*)hrawb)[j] = u;
    #pragma unroll
    for (int h = 0; h < 2; ++h) {
      int i = 2*j + h;
      ushort_t us = (ushort_t)(h ? (u >> 16) : (u & 0xffff));
      ushort_t ur = (us & 0x8000) ? (ushort_t)0 : us;   // relu on bf16
      int ci = i / 49, p = i % 49, y = p / 7, xx = p % 7;
      int ppix = (y + 1)*12 + (xx + 1);
      int byte = ((ppix << 6) + (ci << 1)) ^ ((ppix & 6) << 3);
      *(ushort_t*)(pinc + byte) = ur;
    }
  }
  __syncthreads();

  // conv3x3 via 9 offset-GEMMs, K=32(ci): D[pixel][co]
  fx4 acc[4];
  #pragma unroll
  for (int mt = 0; mt < 4; ++mt) acc[mt] = (fx4){0.f, 0.f, 0.f, 0.f};
  int pb[4];
  #pragma unroll
  for (int mt = 0; mt < 4; ++mt) {
    int p = mt*16 + (l & 15); if (p > 48) p = 48;
    pb[mt] = (p / 7)*12 + (p % 7);
  }
  #pragma unroll
  for (int mt = 0; mt < 4; ++mt) {
    #pragma unroll
    for (int o = 0; o < 9; ++o) {
      int ppix = pb[mt] + (o / 3)*12 + (o % 3);
      int byte = ((ppix << 6) + (g << 4)) ^ ((ppix & 6) << 3);
      short8 afr = *(const short8*)(pinc + byte);
      acc[mt] = __builtin_amdgcn_mfma_f32_16x16x32_bf16(afr, bfr[o], acc[mt], 0, 0, 0);
    }
  }
  // store relu(conv3x3) to rl (bf16, swizzled)
  char* rlc = (char*)rl;
  #pragma unroll
  for (int mt = 0; mt < 4; ++mt) {
    #pragma unroll
    for (int i = 0; i < 4; ++i) {
      int pixr = mt*16 + g*4 + i;
      int co2 = w*16 + (l & 15);
      int byte = ((pixr << 7) + (co2 << 1)) ^ ((pixr & 7) << 4);
      *(ushort_t*)(rlc + byte) = f2bf(fmaxf(acc[mt][i], 0.f));
    }
  }
  __syncthreads();

  // conv1x1: M=64(pixels, wave w owns rows w*16..+16), K=64, N=32
  fx4 a1[2];
  a1[0] = (fx4){0.f,0.f,0.f,0.f}; a1[1] = (fx4){0.f,0.f,0.f,0.f};
  int pr = w*16 + (l & 15);
  #pragma unroll
  for (int kf = 0; kf < 2; ++kf) {
    int byte = ((pr << 7) + (kf << 6) + (g << 4)) ^ ((pr & 7) << 4);
    short8 ar = *(const short8*)(rlc + byte);
    #pragma unroll
    for (int nt = 0; nt < 2; ++nt) {
      short8 br = *(const short8*)(w2b + (size_t)(nt*16 + (l & 15))*64 + kf*32 + g*8);
      a1[nt] = __builtin_amdgcn_mfma_f32_16x16x32_bf16(ar, br, a1[nt], 0, 0, 0);
    }
  }
  // residual + relu -> outl
  #pragma unroll
  for (int nt = 0; nt < 2; ++nt) {
    #pragma unroll
    for (int i = 0; i < 4; ++i) {
      int pix = w*16 + g*4 + i;
      if (pix < 49) {
        int co2 = nt*16 + (l & 15);
        int idx2 = co2*49 + pix;
        float v = bf2f(hrawb[idx2]) + a1[nt][i];
        outl[idx2] = f2bf(fmaxf(v, 0.f));
      }
    }
  }
  __syncthreads();
  uint_t* dst = (uint_t*)(hb + (size_t)b*1568);
  const uint_t* so = (const uint_t*)outl;
  for (int j = t; j < 784; j += 256) dst[j] = so[j];
}

// MFMA GEMM: C[M,N] = A[M,K](bf16) * Wb[N,K](bf16)^T + bias. BM=64, BN=BNF*16.
// 256 threads = 4 waves; wave w owns rows w*16..+16, all BNF n-tiles.
template<int BNF, bool OUTBF16, bool RELU>
__global__ __launch_bounds__(256) void k_mm(const ushort_t* __restrict__ A,
    const ushort_t* __restrict__ Wb, const float* __restrict__ bias,
    void* __restrict__ C, int M, int N, int K)
{
  __shared__ ushort_t As[2048];   // [64][32] bf16, swizzled (64B rows)
  int t = threadIdx.x, l = t & 63, w = t >> 6, g = l >> 4;
  int m0 = blockIdx.x * 64, n0 = blockIdx.y * (BNF * 16);
  fx4 acc[BNF];
  #pragma unroll
  for (int nt = 0; nt < BNF; ++nt) acc[nt] = (fx4){0.f, 0.f, 0.f, 0.f};
  char* asc = (char*)As;
  int srow = t >> 2, sks = (t & 3) * 8;
  int sbyte = ((srow << 6) + (sks << 1)) ^ ((srow & 6) << 3);
  int arow = w*16 + (l & 15);
  int abyte = ((arow << 6) + (g << 4)) ^ ((arow & 6) << 3);
  for (int k0 = 0; k0 < K; k0 += 32) {
    short8 av = *(const short8*)(A + (size_t)(m0 + srow)*K + k0 + sks);
    __syncthreads();
    *(short8*)(asc + sbyte) = av;
    __syncthreads();
    short8 afr = *(const short8*)(asc + abyte);
    #pragma unroll
    for (int nt = 0; nt < BNF; ++nt) {
      short8 bfr = *(const short8*)(Wb + (size_t)(n0 + nt*16 + (l & 15))*K + k0 + g*8);
      acc[nt] = __builtin_amdgcn_mfma_f32_16x16x32_bf16(afr, bfr, acc[nt], 0, 0, 0);
    }
  }
  #pragma unroll
  for (int nt = 0; nt < BNF; ++nt) {
    int col = n0 + nt*16 + (l & 15);
    float bv = bias[col];
    #pragma unroll
    for (int i = 0; i < 4; ++i) {
      int row = m0 + w*16 + g*4 + i;
      float v = acc[nt][i] + bv;
      if (RELU) v = fmaxf(v, 0.f);
      if (OUTBF16) ((ushort_t*)C)[(size_t)row*N + col] = f2bf(v);
      else         ((float*)C)[(size_t)row*N + col] = v;
    }
  }
}

// VQ assign: per-row argmin over 512 codes, zq gather (bf16 out), commit-loss partial sum.
__global__ __launch_bounds__(256) void k_vq_assign(const float* __restrict__ z,
    const float* __restrict__ emb, ushort_t* __restrict__ zqb, int* __restrict__ idx,
    float* __restrict__ loss)
{
  __shared__ float esq[512];
  int t = threadIdx.x;
  int n = blockIdx.x * 256 + t;
  for (int e = t; e < 512; e += 256) {
    const float4* ep = (const float4*)&emb[e*32];
    float s = 0.f;
    #pragma unroll
    for (int q = 0; q < 8; ++q) { float4 v = ep[q]; s += v.x*v.x + v.y*v.y + v.z*v.z + v.w*v.w; }
    esq[e] = s;
  }
  __syncthreads();
  float zv[32];
  const float4* zp = (const float4*)&z[n*32];
  float zz = 0.f;
  #pragma unroll
  for (int q = 0; q < 8; ++q) {
    float4 v = zp[q];
    zv[4*q]=v.x; zv[4*q+1]=v.y; zv[4*q+2]=v.z; zv[4*q+3]=v.w;
    zz += v.x*v.x + v.y*v.y + v.z*v.z + v.w*v.w;
  }
  float best = 3.4e38f; int bi = 0;
  for (int e = 0; e < 512; ++e) {
    const float4* ep = (const float4*)&emb[e*32];
    float dot = 0.f;
    #pragma unroll
    for (int q = 0; q < 8; ++q) {
      float4 v = ep[q];
      dot += zv[4*q]*v.x + zv[4*q+1]*v.y + zv[4*q+2]*v.z + zv[4*q+3]*v.w;
    }
    float d = zz + esq[e] - 2.f*dot;
    if (d < best) { best = d; bi = e; }
  }
  idx[n] = bi;
  const float4* bp = (const float4*)&emb[bi*32];
  uint_t* zo = (uint_t*)(zqb + (size_t)n*32);
  float ls = 0.f;
  #pragma unroll
  for (int q = 0; q < 8; ++q) {
    float4 v = bp[q];
    zo[q*2]   = (uint_t)f2bf(v.x) | ((uint_t)f2bf(v.y) << 16);
    zo[q*2+1] = (uint_t)f2bf(v.z) | ((uint_t)f2bf(v.w) << 16);
    float d0 = v.x - zv[4*q], d1 = v.y - zv[4*q+1];
    float d2 = v.z - zv[4*q+2], d3 = v.w - zv[4*q+3];
    ls += d0*d0 + d1*d1 + d2*d2 + d3*d3;
  }
  #pragma unroll
  for (int m = 32; m >= 1; m >>= 1) ls += __shfl_xor(ls, m);
  if ((t & 63) == 0) atomicAdd(loss, ls);
}

// Per-code segment reduction: counts[e], sums[e][32]. One wave per code.
__global__ __launch_bounds__(64) void k_vq_reduce(const int* __restrict__ idx,
    const float* __restrict__ z, float* __restrict__ counts, float* __restrict__ sums)
{
  int e = blockIdx.x, t = threadIdx.x;
  float cnt = 0.f, sv[32];
  #pragma unroll
  for (int k = 0; k < 32; ++k) sv[k] = 0.f;
  for (int n = t; n < 16384; n += 64) {
    if (idx[n] == e) {
      cnt += 1.f;
      const float4* zp = (const float4*)&z[n*32];
      #pragma unroll
      for (int q = 0; q < 8; ++q) {
        float4 v = zp[q];
        sv[4*q] += v.x; sv[4*q+1] += v.y; sv[4*q+2] += v.z; sv[4*q+3] += v.w;
      }
    }
  }
  #pragma unroll
  for (int m = 32; m >= 1; m >>= 1) {
    cnt += __shfl_xor(cnt, m);
    #pragma unroll
    for (int k = 0; k < 32; ++k) sv[k] += __shfl_xor(sv[k], m);
  }
  if (t == 0) {
    counts[e] = cnt;
    #pragma unroll
    for (int k = 0; k < 32; ++k) sums[e*32 + k] = sv[k];
  }
}

// EMA update, emb_new, perplexity, losses.
__global__ __launch_bounds__(512) void k_vq_final(const float* __restrict__ counts,
    const float* __restrict__ sums, const float* __restrict__ n_mat,
    const float* __restrict__ m_mat, const float* __restrict__ loss,
    float* __restrict__ out)
{
  __shared__ float red[8];
  int t = threadIdx.x;
  float c = counts[t];
  float nn = n_mat[t]*0.99f + c*0.01f;
  #pragma unroll
  for (int k = 0; k < 32; ++k) {
    float mn = m_mat[t*32+k]*0.99f + sums[t*32+k]*0.01f;
    out[12845059 + t*32 + k] = mn / nn;
  }
  float em = c * (1.f/16384.f);
  float ht = em * logf(em + 1e-10f);
  #pragma unroll
  for (int m = 32; m >= 1; m >>= 1) ht += __shfl_xor(ht, m);
  if ((t & 63) == 0) red[t >> 6] = ht;
  __syncthreads();
  if (t == 0) {
    float H = 0.f;
    #pragma unroll
    for (int i = 0; i < 8; ++i) H += red[i];
    float q = loss[0] * (1.f/524288.f);
    out[12845056] = q;           // quant_loss
    out[12845057] = q;           // commit_loss (BETA = 1.0)
    out[12845058] = expf(-H);    // perplexity
  }
}

// Fused decoder: convT1(32->16,k4s2p1)+relu -> convT2(16->1,k4s2p1). bf16 in, fp32 out.
__global__ __launch_bounds__(512) void k_dec(const ushort_t* __restrict__ h5,
    const float* __restrict__ wT1, const float* __restrict__ bt1,
    const float* __restrict__ wt2, const float* __restrict__ bt2,
    float* __restrict__ out)
{
  __shared__ float pin[32][9][12];
  __shared__ float pt1[16][16][16];
  int b = blockIdx.x, t = threadIdx.x;
  float* ps = &pin[0][0][0];
  for (int i = t; i < 3456; i += 512) ps[i] = 0.f;
  float* pq = &pt1[0][0][0];
  for (int i = t; i < 4096; i += 512) pq[i] = 0.f;
  __syncthreads();
  const ushort_t* src = h5 + (size_t)b*1568;
  for (int i = t; i < 1568; i += 512) {
    int ci = i / 49, p = i % 49, y = p / 7, xx = p % 7;
    pin[ci][y+1][xx+1] = bf2f(src[i]);
  }
  __syncthreads();
  {
    int co = t & 15, rest = t >> 4;
    int pc = rest >> 3, yy = rest & 7;
    int py = pc >> 1, px = pc & 1;
    if (yy < 7) {
      float acc[7];
      float bv = bt1[co];
      #pragma unroll
      for (int j = 0; j < 7; ++j) acc[j] = bv;
      for (int ci = 0; ci < 32; ++ci) {
        #pragma unroll
        for (int r = 0; r < 2; ++r) {
          const float* rowp = &pin[ci][yy + py + r][px];
          float fr[8];
          #pragma unroll
          for (int u = 0; u < 8; ++u) fr[u] = rowp[u];
          int ky = 3 - py - 2*r;
          #pragma unroll
          for (int cc = 0; cc < 2; ++cc) {
            int kx = 3 - px - 2*cc;
            float wv = wT1[(ci*16 + ky*4 + kx)*16 + co];
            #pragma unroll
            for (int xx = 0; xx < 7; ++xx)
              acc[xx] += fr[xx + cc] * wv;
          }
        }
      }
      int oy = 2*yy + py;
      #pragma unroll
      for (int xx = 0; xx < 7; ++xx) {
        int ox = 2*xx + px;
        pt1[co][oy + 1][ox + 1] = fmaxf(acc[xx], 0.f);
      }
    }
  }
  __syncthreads();
  for (int p = t; p < 784; p += 512) {
    int oy = p / 28, ox = p % 28;
    int qy = (oy + 1) & 1, qx = (ox + 1) & 1;
    int iy1 = (oy + 1 - qy) >> 1, iy2 = iy1 - 1;
    int ix1 = (ox + 1 - qx) >> 1, ix2 = ix1 - 1;
    float acc = bt2[0];
    #pragma unroll
    for (int ci = 0; ci < 16; ++ci) {
      const float* wc = wt2 + ci*16;
      acc += pt1[ci][iy1+1][ix1+1] * wc[qy*4 + qx]
           + pt1[ci][iy1+1][ix2+1] * wc[qy*4 + qx + 2]
           + pt1[ci][iy2+1][ix1+1] * wc[(qy+2)*4 + qx]
           + pt1[ci][iy2+1][ix2+1] * wc[(qy+2)*4 + qx + 2];
    }
    out[(size_t)b*784 + p] = acc;
  }
}

extern "C" void kernel_launch(void* const* d_in, const int* in_sizes, int n_in,
                              void* d_out, int out_size, void* d_ws, size_t ws_size,
                              hipStream_t stream)
{
  const float* x    = (const float*)d_in[0];
  const float* c1w  = (const float*)d_in[1];
  const float* c1b  = (const float*)d_in[2];
  const float* c2w  = (const float*)d_in[3];
  const float* c2b  = (const float*)d_in[4];
  const float* r1w1 = (const float*)d_in[5];
  const float* r1w2 = (const float*)d_in[6];
  const float* fc1w = (const float*)d_in[7];
  const float* fc1b = (const float*)d_in[8];
  const float* fc2w = (const float*)d_in[9];
  const float* fc2b = (const float*)d_in[10];
  const float* emb  = (const float*)d_in[11];
  const float* nmat = (const float*)d_in[12];
  const float* mmat = (const float*)d_in[13];
  const float* fc3w = (const float*)d_in[14];
  const float* fc3b = (const float*)d_in[15];
  const float* fc4w = (const float*)d_in[16];
  const float* fc4b = (const float*)d_in[17];
  const float* r2w1 = (const float*)d_in[18];
  const float* r2w2 = (const float*)d_in[19];
  const float* t1w  = (const float*)d_in[20];
  const float* t1b  = (const float*)d_in[21];
  const float* t2w  = (const float*)d_in[22];
  const float* t2b  = (const float*)d_in[23];
  float* ws  = (float*)d_ws;
  float* out = (float*)d_out;

  ushort_t* hb   = (ushort_t*)(ws + OFF_HB);
  ushort_t* f1b  = (ushort_t*)(ws + OFF_F1B);
  ushort_t* f3b  = (ushort_t*)(ws + OFF_F3B);
  float*    z    = ws + OFF_Z;
  int*      idx  = (int*)(ws + OFF_IDX);
  ushort_t* zqb  = (ushort_t*)(ws + OFF_ZQB);
  float*    cnts = ws + OFF_CNT;
  float*    sums = ws + OFF_SUM;
  float*    loss = ws + OFF_LOSS;
  float*    wc2  = ws + OFF_WC2;
  float*    wt1  = ws + OFF_WT1;
  ushort_t* wr1b = (ushort_t*)(ws + OFF_WR1B);
  ushort_t* wr2b = (ushort_t*)(ws + OFF_WR2B);
  ushort_t* w2b1 = (ushort_t*)(ws + OFF_W2B1);
  ushort_t* w2b2 = (ushort_t*)(ws + OFF_W2B2);
  ushort_t* fc1wb = (ushort_t*)(ws + OFF_FC1WB);
  ushort_t* fc2wb = (ushort_t*)(ws + OFF_FC2WB);
  ushort_t* fc3wb = (ushort_t*)(ws + OFF_FC3WB);
  ushort_t* fc4wb = (ushort_t*)(ws + OFF_FC4WB);

  k_prep<<<3024, 256, 0, stream>>>(c2w, r1w1, r1w2, r2w1, r2w2, t1w,
                                   fc1w, fc2w, fc3w, fc4w, ws);
  k_enc<<<NB, 256, 0, stream>>>(x, c1w, c1b, wc2, c2b, hb);
  k_res<<<NB, 256, 0, stream>>>(hb, wr1b, w2b1);
  k_mm<14, true, true><<<dim3(256, 1), 256, 0, stream>>>(hb, fc1wb, fc1b, f1b, 16384, 224, 1568);
  k_mm<2, false, false><<<dim3(256, 1), 256, 0, stream>>>(f1b, fc2wb, fc2b, z, 16384, 32, 224);
  k_vq_assign<<<64, 256, 0, stream>>>(z, emb, zqb, idx, loss);
  k_vq_reduce<<<512, 64, 0, stream>>>(idx, z, cnts, sums);
  k_vq_final<<<1, 512, 0, stream>>>(cnts, sums, nmat, mmat, loss, out);
  k_mm<14, true, true><<<dim3(256, 1), 256, 0, stream>>>(zqb, fc3wb, fc3b, f3b, 16384, 224, 32);
  k_mm<14, true, true><<<dim3(256, 7), 256, 0, stream>>>(f3b, fc4wb, fc4b, hb, 16384, 1568, 224);
  k_res<<<NB, 256, 0, stream>>>(hb, wr2b, w2b2);
  k_dec<<<NB, 512, 0, stream>>>(hb, wt1, t1b, t2w, t2b, out);
}

// Round 4
// 986.988 us; speedup vs baseline: 3.3833x; 1.6204x over previous
//
#include <hip/hip_runtime.h>
#include <math.h>

#define NB 16384
typedef unsigned short ushort_t;
typedef unsigned int uint_t;
typedef __attribute__((ext_vector_type(8))) short short8;
typedef __attribute__((ext_vector_type(4))) float fx4;

// ---- ws float offsets (total 17,730,112 floats = 70.9 MB) ----
static const size_t OFF_HB    = 0;          // ushort[16384*1568] bf16 (h2/h3/h4/h5)
static const size_t OFF_F1B   = 12845056;   // ushort[16384*224]
static const size_t OFF_F3B   = 14680064;   // ushort[16384*224]
static const size_t OFF_Z     = 16515072;   // float[524288]
static const size_t OFF_IDX   = 17039360;   // int[16384]
static const size_t OFF_ZQB   = 17055744;   // ushort[524288]
static const size_t OFF_CNT   = 17317888;   // float[512]
static const size_t OFF_SUM   = 17318400;   // float[16384]
static const size_t OFF_LOSS  = 17334784;   // float[64]
static const size_t OFF_WENC  = 17334848;   // ushort[8192] [8kb][32co][32k]
static const size_t OFF_WT1B  = 17343040;   // ushort[8192] [16kk][16co][32ci]
static const size_t OFF_WR1B  = 17351232;   // ushort[18432]  [9][64][32]
static const size_t OFF_WR2B  = 17360448;   // ushort[18432]
static const size_t OFF_W2B1  = 17369664;   // ushort[2048]   [32][64]
static const size_t OFF_W2B2  = 17370688;   // ushort[2048]
static const size_t OFF_FC1WB = 17371712;   // ushort[351232] [224][1568]
static const size_t OFF_FC2WB = 17547328;   // ushort[7168]   [32][224]
static const size_t OFF_FC3WB = 17550912;   // ushort[7168]   [224][32]
static const size_t OFF_FC4WB = 17554496;   // ushort[351232] [1568][224]

static __device__ __forceinline__ ushort_t f2bf(float f) {
  union { float f; uint_t u; } v; v.f = f;
  return (ushort_t)((v.u + 0x7fffu + ((v.u >> 16) & 1u)) >> 16);
}
static __device__ __forceinline__ float bf2f(ushort_t h) {
  union { uint_t u; float f; } v; v.u = ((uint_t)h) << 16;
  return v.f;
}

// Weight prep: transposes + fp32->bf16 conversions; zero loss accumulator.
__global__ __launch_bounds__(256) void k_prep(
    const float* __restrict__ c2w, const float* __restrict__ r1w1,
    const float* __restrict__ r1w2, const float* __restrict__ r2w1,
    const float* __restrict__ r2w2, const float* __restrict__ t1w,
    const float* __restrict__ fc1w, const float* __restrict__ fc2w,
    const float* __restrict__ fc3w, const float* __restrict__ fc4w,
    float* __restrict__ ws)
{
  int gid = blockIdx.x * 256 + threadIdx.x;
  if (gid == 0) ws[OFF_LOSS] = 0.f;
  if (gid >= 774144) return;
  ushort_t* wencb = (ushort_t*)(ws + OFF_WENC);
  ushort_t* wt1b  = (ushort_t*)(ws + OFF_WT1B);
  ushort_t* wr1b  = (ushort_t*)(ws + OFF_WR1B);
  ushort_t* wr2b  = (ushort_t*)(ws + OFF_WR2B);
  ushort_t* w2b1  = (ushort_t*)(ws + OFF_W2B1);
  ushort_t* w2b2  = (ushort_t*)(ws + OFF_W2B2);
  ushort_t* fc1wb = (ushort_t*)(ws + OFF_FC1WB);
  ushort_t* fc2wb = (ushort_t*)(ws + OFF_FC2WB);
  ushort_t* fc3wb = (ushort_t*)(ws + OFF_FC3WB);
  ushort_t* fc4wb = (ushort_t*)(ws + OFF_FC4WB);
  int i = gid;
  if (i < 8192) {            // conv2 MFMA weights: [kb=ky*2+k2][co32][k=kxs*16+ci]
    int kidx = i & 31, rest = i >> 5, co = rest & 31, kb = rest >> 5;
    int ky = kb >> 1, k2 = kb & 1, kxs = kidx >> 4, ci = kidx & 15;
    wencb[i] = f2bf(c2w[co*256 + ci*16 + ky*4 + 2*k2 + kxs]);
  } else if (i < 16384) {    // convT1 MFMA weights: [kk16][co16][ci32]
    int j = i - 8192, ci = j & 31, rest = j >> 5, co = rest & 15, kk = rest >> 4;
    wt1b[j] = f2bf(t1w[ci*256 + co*16 + kk]);
  } else if (i < 34816) {    // res1 w1 -> [kk][co][ci] bf16
    int j = i - 16384, ci = j & 31, r = j >> 5, co = r & 63, kk = r >> 6;
    wr1b[j] = f2bf(r1w1[co*288 + ci*9 + kk]);
  } else if (i < 53248) {    // res2 w1
    int j = i - 34816, ci = j & 31, r = j >> 5, co = r & 63, kk = r >> 6;
    wr2b[j] = f2bf(r2w1[co*288 + ci*9 + kk]);
  } else if (i < 55296) {    // res1 w2 [32][64] bf16
    int j = i - 53248; w2b1[j] = f2bf(r1w2[j]);
  } else if (i < 57344) {    // res2 w2
    int j = i - 55296; w2b2[j] = f2bf(r2w2[j]);
  } else if (i < 408576) {   // fc1 [224][1568]
    int j = i - 57344; fc1wb[j] = f2bf(fc1w[j]);
  } else if (i < 415744) {   // fc2 [32][224]
    int j = i - 408576; fc2wb[j] = f2bf(fc2w[j]);
  } else if (i < 422912) {   // fc3 [224][32]
    int j = i - 415744; fc3wb[j] = f2bf(fc3w[j]);
  } else {                   // fc4 [1568][224]
    int j = i - 422912; fc4wb[j] = f2bf(fc4w[j]);
  }
}

// Fused encoder: conv1(1->16,k4s2p1)+relu (VALU) -> conv2(16->32,k4s2p1) (MFMA).
// One image/block, 256 threads = 4 waves.
__global__ __launch_bounds__(256) void k_enc(const float* __restrict__ x,
    const float* __restrict__ w1, const float* __restrict__ b1,
    const ushort_t* __restrict__ wencb, const float* __restrict__ b2,
    ushort_t* __restrict__ hb)
{
  __shared__ float xin[30][32];          // x padded
  __shared__ ushort_t ph1b[256*24];      // [prow=piy*16+pix][ci16] bf16, 48B row stride
  __shared__ ushort_t outl[1568];
  int b = blockIdx.x, t = threadIdx.x, l = t & 63, w = t >> 6;
  int pr = l & 15, g = l >> 4;
  // preload conv2 B-frags (overlaps conv1 compute)
  short8 bf[8][2];
  #pragma unroll
  for (int kb = 0; kb < 8; ++kb)
    #pragma unroll
    for (int nt = 0; nt < 2; ++nt)
      bf[kb][nt] = *(const short8*)(wencb + (size_t)(kb*32 + nt*16 + pr)*32 + g*8);
  uint_t* pz = (uint_t*)ph1b;
  for (int i = t; i < 3072; i += 256) pz[i] = 0;
  float* xp = &xin[0][0];
  for (int i = t; i < 960; i += 256) xp[i] = 0.f;
  __syncthreads();
  const float* xb = x + (size_t)b*784;
  for (int i = t; i < 784; i += 256) xin[i/28 + 1][i%28 + 1] = xb[i];
  __syncthreads();
  // conv1: thread computes (pixel p, channel co); lanes 0-15 share p -> xin broadcast
  char* phc = (char*)ph1b;
  for (int i = t; i < 3136; i += 256) {
    int p = i >> 4, co = i & 15, oy = p/14, ox = p%14;
    float acc = b1[co];
    #pragma unroll
    for (int ky = 0; ky < 4; ++ky)
      #pragma unroll
      for (int kx = 0; kx < 4; ++kx)
        acc += xin[2*oy+ky][2*ox+kx] * w1[co*16 + ky*4 + kx];
    int prow = (oy+1)*16 + (ox+1);
    *(ushort_t*)(phc + prow*48 + co*2) = f2bf(fmaxf(acc, 0.f));
  }
  __syncthreads();
  // conv2 MFMA: wave w = M-tile; 8 k-blocks (ky x kx-pair), 2 n-tiles
  int p = w*16 + pr; if (p > 48) p = 48;
  int oy = p/7, ox = p%7;
  fx4 acc2[2];
  acc2[0] = (fx4){0.f,0.f,0.f,0.f}; acc2[1] = (fx4){0.f,0.f,0.f,0.f};
  #pragma unroll
  for (int kb = 0; kb < 8; ++kb) {
    int ky = kb >> 1, k2 = kb & 1;
    int prow = (2*oy + ky)*16 + 2*ox + 2*k2 + (g >> 1);
    short8 afr = *(const short8*)(phc + prow*48 + (g & 1)*16);
    acc2[0] = __builtin_amdgcn_mfma_f32_16x16x32_bf16(afr, bf[kb][0], acc2[0], 0, 0, 0);
    acc2[1] = __builtin_amdgcn_mfma_f32_16x16x32_bf16(afr, bf[kb][1], acc2[1], 0, 0, 0);
  }
  #pragma unroll
  for (int nt = 0; nt < 2; ++nt) {
    int co = nt*16 + pr;
    float bv = b2[co];
    #pragma unroll
    for (int i = 0; i < 4; ++i) {
      int pix = w*16 + g*4 + i;
      if (pix < 49) outl[co*49 + pix] = f2bf(acc2[nt][i] + bv);
    }
  }
  __syncthreads();
  uint_t* dst = (uint_t*)(hb + (size_t)b*1568);
  const uint_t* so = (const uint_t*)outl;
  for (int j = t; j < 784; j += 256) dst[j] = so[j];
}

// MFMA residual stack: relu -> conv3x3(32->64) -> relu -> conv1x1(64->32) -> +x -> relu.
// In/out bf16 [b][32][49], in-place. 256 threads = 4 waves per image.
__global__ __launch_bounds__(256) void k_res(ushort_t* __restrict__ hb,
    const ushort_t* __restrict__ wrb, const ushort_t* __restrict__ w2b)
{
  __shared__ ushort_t pinT[3456];   // [pp=108][ci=32], swizzled (64B rows)
  __shared__ ushort_t rl[4096];     // [pix=64][co=64], swizzled (128B rows)
  __shared__ ushort_t hrawb[1568];
  __shared__ ushort_t outl[1568];
  int b = blockIdx.x, t = threadIdx.x, l = t & 63, w = t >> 6, g = l >> 4;

  short8 bfr[9];
  #pragma unroll
  for (int o = 0; o < 9; ++o)
    bfr[o] = *(const short8*)(wrb + (size_t)(o*64 + w*16 + (l & 15))*32 + g*8);

  uint_t* pz = (uint_t*)pinT;
  for (int i = t; i < 1728; i += 256) pz[i] = 0;
  __syncthreads();

  const uint_t* src = (const uint_t*)(hb + (size_t)b*1568);
  char* pinc = (char*)pinT;
  for (int j = t; j < 784; j += 256) {
    uint_t u = src[j];
    ((uint_t*)hrawb)[j] = u;
    #pragma unroll
    for (int h = 0; h < 2; ++h) {
      int i = 2*j + h;
      ushort_t us = (ushort_t)(h ? (u >> 16) : (u & 0xffff));
      ushort_t ur = (us & 0x8000) ? (ushort_t)0 : us;   // relu on bf16
      int ci = i / 49, p = i % 49, y = p / 7, xx = p % 7;
      int ppix = (y + 1)*12 + (xx + 1);
      int byte = ((ppix << 6) + (ci << 1)) ^ ((ppix & 6) << 3);
      *(ushort_t*)(pinc + byte) = ur;
    }
  }
  __syncthreads();

  fx4 acc[4];
  #pragma unroll
  for (int mt = 0; mt < 4; ++mt) acc[mt] = (fx4){0.f, 0.f, 0.f, 0.f};
  int pb[4];
  #pragma unroll
  for (int mt = 0; mt < 4; ++mt) {
    int p = mt*16 + (l & 15); if (p > 48) p = 48;
    pb[mt] = (p / 7)*12 + (p % 7);
  }
  #pragma unroll
  for (int mt = 0; mt < 4; ++mt) {
    #pragma unroll
    for (int o = 0; o < 9; ++o) {
      int ppix = pb[mt] + (o / 3)*12 + (o % 3);
      int byte = ((ppix << 6) + (g << 4)) ^ ((ppix & 6) << 3);
      short8 afr = *(const short8*)(pinc + byte);
      acc[mt] = __builtin_amdgcn_mfma_f32_16x16x32_bf16(afr, bfr[o], acc[mt], 0, 0, 0);
    }
  }
  char* rlc = (char*)rl;
  #pragma unroll
  for (int mt = 0; mt < 4; ++mt) {
    #pragma unroll
    for (int i = 0; i < 4; ++i) {
      int pixr = mt*16 + g*4 + i;
      int co2 = w*16 + (l & 15);
      int byte = ((pixr << 7) + (co2 << 1)) ^ ((pixr & 7) << 4);
      *(ushort_t*)(rlc + byte) = f2bf(fmaxf(acc[mt][i], 0.f));
    }
  }
  __syncthreads();

  fx4 a1[2];
  a1[0] = (fx4){0.f,0.f,0.f,0.f}; a1[1] = (fx4){0.f,0.f,0.f,0.f};
  int prr = w*16 + (l & 15);
  #pragma unroll
  for (int kf = 0; kf < 2; ++kf) {
    int byte = ((prr << 7) + (kf << 6) + (g << 4)) ^ ((prr & 7) << 4);
    short8 ar = *(const short8*)(rlc + byte);
    #pragma unroll
    for (int nt = 0; nt < 2; ++nt) {
      short8 br = *(const short8*)(w2b + (size_t)(nt*16 + (l & 15))*64 + kf*32 + g*8);
      a1[nt] = __builtin_amdgcn_mfma_f32_16x16x32_bf16(ar, br, a1[nt], 0, 0, 0);
    }
  }
  #pragma unroll
  for (int nt = 0; nt < 2; ++nt) {
    #pragma unroll
    for (int i = 0; i < 4; ++i) {
      int pix = w*16 + g*4 + i;
      if (pix < 49) {
        int co2 = nt*16 + (l & 15);
        int idx2 = co2*49 + pix;
        float v = bf2f(hrawb[idx2]) + a1[nt][i];
        outl[idx2] = f2bf(fmaxf(v, 0.f));
      }
    }
  }
  __syncthreads();
  uint_t* dst = (uint_t*)(hb + (size_t)b*1568);
  const uint_t* so = (const uint_t*)outl;
  for (int j = t; j < 784; j += 256) dst[j] = so[j];
}

// MFMA GEMM: C[M,N] = A[M,K](bf16) * Wb[N,K](bf16)^T + bias. BM=64, BN=BNF*16.
template<int BNF, bool OUTBF16, bool RELU>
__global__ __launch_bounds__(256) void k_mm(const ushort_t* __restrict__ A,
    const ushort_t* __restrict__ Wb, const float* __restrict__ bias,
    void* __restrict__ C, int M, int N, int K)
{
  __shared__ ushort_t As[2048];   // [64][32] bf16, swizzled (64B rows)
  int t = threadIdx.x, l = t & 63, w = t >> 6, g = l >> 4;
  int m0 = blockIdx.x * 64, n0 = blockIdx.y * (BNF * 16);
  fx4 acc[BNF];
  #pragma unroll
  for (int nt = 0; nt < BNF; ++nt) acc[nt] = (fx4){0.f, 0.f, 0.f, 0.f};
  char* asc = (char*)As;
  int srow = t >> 2, sks = (t & 3) * 8;
  int sbyte = ((srow << 6) + (sks << 1)) ^ ((srow & 6) << 3);
  int arow = w*16 + (l & 15);
  int abyte = ((arow << 6) + (g << 4)) ^ ((arow & 6) << 3);
  for (int k0 = 0; k0 < K; k0 += 32) {
    short8 av = *(const short8*)(A + (size_t)(m0 + srow)*K + k0 + sks);
    __syncthreads();
    *(short8*)(asc + sbyte) = av;
    __syncthreads();
    short8 afr = *(const short8*)(asc + abyte);
    #pragma unroll
    for (int nt = 0; nt < BNF; ++nt) {
      short8 bfr = *(const short8*)(Wb + (size_t)(n0 + nt*16 + (l & 15))*K + k0 + g*8);
      acc[nt] = __builtin_amdgcn_mfma_f32_16x16x32_bf16(afr, bfr, acc[nt], 0, 0, 0);
    }
  }
  #pragma unroll
  for (int nt = 0; nt < BNF; ++nt) {
    int col = n0 + nt*16 + (l & 15);
    float bv = bias[col];
    #pragma unroll
    for (int i = 0; i < 4; ++i) {
      int row = m0 + w*16 + g*4 + i;
      float v = acc[nt][i] + bv;
      if (RELU) v = fmaxf(v, 0.f);
      if (OUTBF16) ((ushort_t*)C)[(size_t)row*N + col] = f2bf(v);
      else         ((float*)C)[(size_t)row*N + col] = v;
    }
  }
}

// VQ assign: per-row argmin over 512 codes, zq gather (bf16 out), commit-loss partial sum.
__global__ __launch_bounds__(256) void k_vq_assign(const float* __restrict__ z,
    const float* __restrict__ emb, ushort_t* __restrict__ zqb, int* __restrict__ idx,
    float* __restrict__ loss)
{
  __shared__ float esq[512];
  int t = threadIdx.x;
  int n = blockIdx.x * 256 + t;
  for (int e = t; e < 512; e += 256) {
    const float4* ep = (const float4*)&emb[e*32];
    float s = 0.f;
    #pragma unroll
    for (int q = 0; q < 8; ++q) { float4 v = ep[q]; s += v.x*v.x + v.y*v.y + v.z*v.z + v.w*v.w; }
    esq[e] = s;
  }
  __syncthreads();
  float zv[32];
  const float4* zp = (const float4*)&z[n*32];
  float zz = 0.f;
  #pragma unroll
  for (int q = 0; q < 8; ++q) {
    float4 v = zp[q];
    zv[4*q]=v.x; zv[4*q+1]=v.y; zv[4*q+2]=v.z; zv[4*q+3]=v.w;
    zz += v.x*v.x + v.y*v.y + v.z*v.z + v.w*v.w;
  }
  float best = 3.4e38f; int bi = 0;
  for (int e = 0; e < 512; ++e) {
    const float4* ep = (const float4*)&emb[e*32];
    float dot = 0.f;
    #pragma unroll
    for (int q = 0; q < 8; ++q) {
      float4 v = ep[q];
      dot += zv[4*q]*v.x + zv[4*q+1]*v.y + zv[4*q+2]*v.z + zv[4*q+3]*v.w;
    }
    float d = zz + esq[e] - 2.f*dot;
    if (d < best) { best = d; bi = e; }
  }
  idx[n] = bi;
  const float4* bp = (const float4*)&emb[bi*32];
  uint_t* zo = (uint_t*)(zqb + (size_t)n*32);
  float ls = 0.f;
  #pragma unroll
  for (int q = 0; q < 8; ++q) {
    float4 v = bp[q];
    zo[q*2]   = (uint_t)f2bf(v.x) | ((uint_t)f2bf(v.y) << 16);
    zo[q*2+1] = (uint_t)f2bf(v.z) | ((uint_t)f2bf(v.w) << 16);
    float d0 = v.x - zv[4*q], d1 = v.y - zv[4*q+1];
    float d2 = v.z - zv[4*q+2], d3 = v.w - zv[4*q+3];
    ls += d0*d0 + d1*d1 + d2*d2 + d3*d3;
  }
  #pragma unroll
  for (int m = 32; m >= 1; m >>= 1) ls += __shfl_xor(ls, m);
  if ((t & 63) == 0) atomicAdd(loss, ls);
}

// Per-code segment reduction: counts[e], sums[e][32]. One wave per code.
__global__ __launch_bounds__(64) void k_vq_reduce(const int* __restrict__ idx,
    const float* __restrict__ z, float* __restrict__ counts, float* __restrict__ sums)
{
  int e = blockIdx.x, t = threadIdx.x;
  float cnt = 0.f, sv[32];
  #pragma unroll
  for (int k = 0; k < 32; ++k) sv[k] = 0.f;
  for (int n = t; n < 16384; n += 64) {
    if (idx[n] == e) {
      cnt += 1.f;
      const float4* zp = (const float4*)&z[n*32];
      #pragma unroll
      for (int q = 0; q < 8; ++q) {
        float4 v = zp[q];
        sv[4*q] += v.x; sv[4*q+1] += v.y; sv[4*q+2] += v.z; sv[4*q+3] += v.w;
      }
    }
  }
  #pragma unroll
  for (int m = 32; m >= 1; m >>= 1) {
    cnt += __shfl_xor(cnt, m);
    #pragma unroll
    for (int k = 0; k < 32; ++k) sv[k] += __shfl_xor(sv[k], m);
  }
  if (t == 0) {
    counts[e] = cnt;
    #pragma unroll
    for (int k = 0; k < 32; ++k) sums[e*32 + k] = sv[k];
  }
}

// EMA update, emb_new, perplexity, losses.
__global__ __launch_bounds__(512) void k_vq_final(const float* __restrict__ counts,
    const float* __restrict__ sums, const float* __restrict__ n_mat,
    const float* __restrict__ m_mat, const float* __restrict__ loss,
    float* __restrict__ out)
{
  __shared__ float red[8];
  int t = threadIdx.x;
  float c = counts[t];
  float nn = n_mat[t]*0.99f + c*0.01f;
  #pragma unroll
  for (int k = 0; k < 32; ++k) {
    float mn = m_mat[t*32+k]*0.99f + sums[t*32+k]*0.01f;
    out[12845059 + t*32 + k] = mn / nn;
  }
  float em = c * (1.f/16384.f);
  float ht = em * logf(em + 1e-10f);
  #pragma unroll
  for (int m = 32; m >= 1; m >>= 1) ht += __shfl_xor(ht, m);
  if ((t & 63) == 0) red[t >> 6] = ht;
  __syncthreads();
  if (t == 0) {
    float H = 0.f;
    #pragma unroll
    for (int i = 0; i < 8; ++i) H += red[i];
    float q = loss[0] * (1.f/524288.f);
    out[12845056] = q;           // quant_loss
    out[12845057] = q;           // commit_loss (BETA = 1.0)
    out[12845058] = expf(-H);    // perplexity
  }
}

// Fused decoder: convT1(32->16,k4s2p1)+relu (MFMA, parity per wave) -> convT2(16->1) (VALU).
// One image/block, 256 threads = 4 waves.
__global__ __launch_bounds__(256) void k_dec(const ushort_t* __restrict__ h5,
    const ushort_t* __restrict__ wt1b, const float* __restrict__ bt1,
    const float* __restrict__ wt2, const float* __restrict__ bt2,
    float* __restrict__ out)
{
  __shared__ ushort_t pinT[3456];     // h5 [ppix=108][ci=32] swizzled (64B rows)
  __shared__ ushort_t pt1b[256*20];   // t1 [prow=(iy+1)*16+(ix+1)][ci16] bf16, 40B stride
  __shared__ float w2l[256];          // convT2 weights [ci][kk]
  __shared__ float outl[784];
  int b = blockIdx.x, t = threadIdx.x, l = t & 63, w = t >> 6;
  int pr = l & 15, g = l >> 4;
  // convT1 B-frags for this wave's parity (py,px)
  int py = w >> 1, px = w & 1;
  short8 bfr[4];
  #pragma unroll
  for (int r = 0; r < 2; ++r)
    #pragma unroll
    for (int c = 0; c < 2; ++c) {
      int kk = (3 - py - 2*r)*4 + (3 - px - 2*c);
      bfr[r*2 + c] = *(const short8*)(wt1b + (size_t)(kk*16 + pr)*32 + g*8);
    }
  uint_t* pz = (uint_t*)pinT;
  for (int i = t; i < 1728; i += 256) pz[i] = 0;
  uint_t* qz = (uint_t*)pt1b;
  for (int i = t; i < 2560; i += 256) qz[i] = 0;
  if (t < 256) w2l[t] = wt2[t];
  __syncthreads();
  // stage h5 (raw, already >=0) into swizzled pinT
  const uint_t* src = (const uint_t*)(h5 + (size_t)b*1568);
  char* pinc = (char*)pinT;
  for (int j = t; j < 784; j += 256) {
    uint_t u = src[j];
    #pragma unroll
    for (int h = 0; h < 2; ++h) {
      int i = 2*j + h;
      ushort_t us = (ushort_t)(h ? (u >> 16) : (u & 0xffff));
      int ci = i / 49, p = i % 49, y = p / 7, xx = p % 7;
      int ppix = (y + 1)*12 + (xx + 1);
      int byte = ((ppix << 6) + (ci << 1)) ^ ((ppix & 6) << 3);
      *(ushort_t*)(pinc + byte) = us;
    }
  }
  __syncthreads();
  // convT1 MFMA: 4 M-tiles x 4 taps, K=32(ci), N=16(co)
  fx4 acc[4];
  #pragma unroll
  for (int mt = 0; mt < 4; ++mt) acc[mt] = (fx4){0.f, 0.f, 0.f, 0.f};
  int pb[4];
  #pragma unroll
  for (int mt = 0; mt < 4; ++mt) {
    int p = mt*16 + pr; if (p > 48) p = 48;
    pb[mt] = (p / 7)*12 + (p % 7);
  }
  #pragma unroll
  for (int mt = 0; mt < 4; ++mt) {
    #pragma unroll
    for (int r = 0; r < 2; ++r)
      #pragma unroll
      for (int c = 0; c < 2; ++c) {
        int ppix = pb[mt] + (py + r)*12 + (px + c);
        int byte = ((ppix << 6) + (g << 4)) ^ ((ppix & 6) << 3);
        short8 afr = *(const short8*)(pinc + byte);
        acc[mt] = __builtin_amdgcn_mfma_f32_16x16x32_bf16(afr, bfr[r*2 + c], acc[mt], 0, 0, 0);
      }
  }
  // epilogue: bias + relu -> pt1b (co = pr)
  char* ptc = (char*)pt1b;
  float bv1 = bt1[pr];
  #pragma unroll
  for (int mt = 0; mt < 4; ++mt) {
    #pragma unroll
    for (int i = 0; i < 4; ++i) {
      int p = mt*16 + g*4 + i;
      if (p < 49) {
        int yy = p / 7, xx = p % 7;
        int opix = (2*yy + py + 1)*16 + (2*xx + px + 1);
        *(ushort_t*)(ptc + opix*40 + pr*2) = f2bf(fmaxf(acc[mt][i] + bv1, 0.f));
      }
    }
  }
  __syncthreads();
  // convT2: wave = output parity class (qy,qx); weights wave-uniform -> registers
  {
    int qy = w >> 1, qx = w & 1;
    float wreg[4][16];
    int kkt[4] = { qy*4 + qx, qy*4 + qx + 2, (qy+2)*4 + qx, (qy+2)*4 + qx + 2 };
    #pragma unroll
    for (int tt = 0; tt < 4; ++tt)
      #pragma unroll
      for (int ci = 0; ci < 16; ++ci)
        wreg[tt][ci] = w2l[ci*16 + kkt[tt]];
    float bv2 = bt2[0];
    #pragma unroll
    for (int k = 0; k < 4; ++k) {
      int j = l + k*64;
      if (j < 196) {
        int a = j / 14, bb = j % 14;
        int oy = 2*a + 1 - qy, ox = 2*bb + 1 - qx;
        int iy1 = a + 1 - qy, iy2 = a - qy;      // ky = qy, qy+2
        int ix1 = bb + 1 - qx, ix2 = bb - qx;    // kx = qx, qx+2
        int prw[4];
        prw[0] = (iy1 + 1)*16 + (ix1 + 1);
        prw[1] = (iy1 + 1)*16 + (ix2 + 1);
        prw[2] = (iy2 + 1)*16 + (ix1 + 1);
        prw[3] = (iy2 + 1)*16 + (ix2 + 1);
        float s = bv2;
        #pragma unroll
        for (int tt = 0; tt < 4; ++tt) {
          #pragma unroll
          for (int jj = 0; jj < 4; ++jj) {
            uint2 v = *(const uint2*)(ptc + prw[tt]*40 + jj*8);
            s += bf2f((ushort_t)(v.x & 0xffff)) * wreg[tt][jj*4+0]
               + bf2f((ushort_t)(v.x >> 16))    * wreg[tt][jj*4+1]
               + bf2f((ushort_t)(v.y & 0xffff)) * wreg[tt][jj*4+2]
               + bf2f((ushort_t)(v.y >> 16))    * wreg[tt][jj*4+3];
          }
        }
        outl[oy*28 + ox] = s;
      }
    }
  }
  __syncthreads();
  float* dst = out + (size_t)b*784;
  for (int i = t; i < 784; i += 256) dst[i] = outl[i];
}

extern "C" void kernel_launch(void* const* d_in, const int* in_sizes, int n_in,
                              void* d_out, int out_size, void* d_ws, size_t ws_size,
                              hipStream_t stream)
{
  const float* x    = (const float*)d_in[0];
  const float* c1w  = (const float*)d_in[1];
  const float* c1b  = (const float*)d_in[2];
  const float* c2w  = (const float*)d_in[3];
  const float* c2b  = (const float*)d_in[4];
  const float* r1w1 = (const float*)d_in[5];
  const float* r1w2 = (const float*)d_in[6];
  const float* fc1w = (const float*)d_in[7];
  const float* fc1b = (const float*)d_in[8];
  const float* fc2w = (const float*)d_in[9];
  const float* fc2b = (const float*)d_in[10];
  const float* emb  = (const float*)d_in[11];
  const float* nmat = (const float*)d_in[12];
  const float* mmat = (const float*)d_in[13];
  const float* fc3w = (const float*)d_in[14];
  const float* fc3b = (const float*)d_in[15];
  const float* fc4w = (const float*)d_in[16];
  const float* fc4b = (const float*)d_in[17];
  const float* r2w1 = (const float*)d_in[18];
  const float* r2w2 = (const float*)d_in[19];
  const float* t1w  = (const float*)d_in[20];
  const float* t1b  = (const float*)d_in[21];
  const float* t2w  = (const float*)d_in[22];
  const float* t2b  = (const float*)d_in[23];
  float* ws  = (float*)d_ws;
  float* out = (float*)d_out;

  ushort_t* hb   = (ushort_t*)(ws + OFF_HB);
  ushort_t* f1b  = (ushort_t*)(ws + OFF_F1B);
  ushort_t* f3b  = (ushort_t*)(ws + OFF_F3B);
  float*    z    = ws + OFF_Z;
  int*      idx  = (int*)(ws + OFF_IDX);
  ushort_t* zqb  = (ushort_t*)(ws + OFF_ZQB);
  float*    cnts = ws + OFF_CNT;
  float*    sums = ws + OFF_SUM;
  float*    loss = ws + OFF_LOSS;
  ushort_t* wencb = (ushort_t*)(ws + OFF_WENC);
  ushort_t* wt1b  = (ushort_t*)(ws + OFF_WT1B);
  ushort_t* wr1b  = (ushort_t*)(ws + OFF_WR1B);
  ushort_t* wr2b  = (ushort_t*)(ws + OFF_WR2B);
  ushort_t* w2b1  = (ushort_t*)(ws + OFF_W2B1);
  ushort_t* w2b2  = (ushort_t*)(ws + OFF_W2B2);
  ushort_t* fc1wb = (ushort_t*)(ws + OFF_FC1WB);
  ushort_t* fc2wb = (ushort_t*)(ws + OFF_FC2WB);
  ushort_t* fc3wb = (ushort_t*)(ws + OFF_FC3WB);
  ushort_t* fc4wb = (ushort_t*)(ws + OFF_FC4WB);

  k_prep<<<3024, 256, 0, stream>>>(c2w, r1w1, r1w2, r2w1, r2w2, t1w,
                                   fc1w, fc2w, fc3w, fc4w, ws);
  k_enc<<<NB, 256, 0, stream>>>(x, c1w, c1b, wencb, c2b, hb);
  k_res<<<NB, 256, 0, stream>>>(hb, wr1b, w2b1);
  k_mm<14, true, true><<<dim3(256, 1), 256, 0, stream>>>(hb, fc1wb, fc1b, f1b, 16384, 224, 1568);
  k_mm<2, false, false><<<dim3(256, 1), 256, 0, stream>>>(f1b, fc2wb, fc2b, z, 16384, 32, 224);
  k_vq_assign<<<64, 256, 0, stream>>>(z, emb, zqb, idx, loss);
  k_vq_reduce<<<512, 64, 0, stream>>>(idx, z, cnts, sums);
  k_vq_final<<<1, 512, 0, stream>>>(cnts, sums, nmat, mmat, loss, out);
  k_mm<14, true, true><<<dim3(256, 1), 256, 0, stream>>>(zqb, fc3wb, fc3b, f3b, 16384, 224, 32);
  k_mm<14, true, true><<<dim3(256, 7), 256, 0, stream>>>(f3b, fc4wb, fc4b, hb, 16384, 1568, 224);
  k_res<<<NB, 256, 0, stream>>>(hb, wr2b, w2b2);
  k_dec<<<NB, 256, 0, stream>>>(hb, wt1b, t1b, t2w, t2b, out);
}